// Round 8
// baseline (258.140 us; speedup 1.0000x reference)
//
#include <hip/hip_runtime.h>
#include <math.h>

// Problem constants (match reference)
constexpr int D_ = 64;
constexpr int N_ = 8192;
constexpr int DIM_ = 256;
constexpr int K_ = 32;
constexpr int L_ = 1;
constexpr int P_ = D_ - L_;  // 63
constexpr float TEMP_ = 0.1f;
constexpr float EPS_ = 1e-8f;

constexpr int CHUNKS = 32;   // blocks per d
constexpr int CROWS = 256;   // rows per chunk (per block)
constexpr int BATCH = 16;    // rows per wave per LDS round
constexpr int LDSTR = 65;    // scratch stride (words) -> 2-way (free) banks

typedef unsigned long long u64;

// Kernel 1: r4's exact streaming structure (150.7us baseline) + sorted
// candidate emission. Per (d,chunk) block: 4 waves x 64 consecutive rows.
// Row-norm keys ((normbits<<32)|(N-1-n)) collect in a SEPARATE 2KB LDS
// array during streaming; after the colsum epilogue a 256-key bitonic sort
// (descending; keys unique) emits this block's sorted top-32. normsq global
// round-trip is gone entirely.
__global__ __launch_bounds__(256, 4) void k1_stream(const float* __restrict__ emb,
                                                    u64* __restrict__ cand,
                                                    float* __restrict__ sum_all) {
  const int b = blockIdx.x;
  const int d = b >> 5;
  const int chunk = b & 31;
  const int tid = threadIdx.x;
  const int wave = tid >> 6;
  const int lane = tid & 63;
  const float* base = emb + (size_t)d * N_ * DIM_;

  __shared__ __align__(16) float sq[4][BATCH * LDSTR];  // 16.25 KB
  __shared__ u64 keys[CROWS];                           // 2 KB

  float a0 = 0.f, a1 = 0.f, a2 = 0.f, a3 = 0.f;
  const int wrow0 = chunk * CROWS + wave * 64;

  for (int batch = 0; batch < 64 / BATCH; ++batch) {
    const int r0 = wrow0 + batch * BATCH;
#pragma unroll
    for (int r = 0; r < BATCH; ++r) {
      const float4 v = *reinterpret_cast<const float4*>(base + (size_t)(r0 + r) * DIM_ + (lane << 2));
      a0 += v.x; a1 += v.y; a2 += v.z; a3 += v.w;
      sq[wave][r * LDSTR + lane] = v.x * v.x + v.y * v.y + v.z * v.z + v.w * v.w;
    }
    // Own-wave transpose-reduce: 4 threads/row, 16 adds each, 2 shfl.
    {
      const int rr = tid >> 2;   // in [16*wave, 16*wave+16)
      const int q = tid & 3;
      const int r = rr & 15;
      const float* p = &sq[wave][r * LDSTR + q * 16];
      float s = 0.f;
#pragma unroll
      for (int i = 0; i < 16; ++i) s += p[i];
      s += __shfl_xor(s, 1, 64);
      s += __shfl_xor(s, 2, 64);
      if (q == 0) {
        const int browid = wave * 64 + batch * BATCH + r;  // local row in [0,256)
        const int n = chunk * CROWS + browid;
        // larger norm wins; tie -> larger (N-1-n) = smaller index (stable argsort)
        keys[browid] = ((u64)__float_as_uint(s) << 32) | (unsigned)(N_ - 1 - n);
      }
    }
  }

  // Colsum epilogue: own-wave stash into sq region, barrier, cross-wave combine.
  reinterpret_cast<float4*>(&sq[wave][0])[lane] = make_float4(a0, a1, a2, a3);
  __syncthreads();
  {
    const float s = sq[0][tid] + sq[1][tid] + sq[2][tid] + sq[3][tid];
    atomicAdd(&sum_all[d * DIM_ + tid], s);
  }

  // Bitonic sort keys[256] descending (keys unique -> total order).
  for (int size = 2; size <= CROWS; size <<= 1) {
    for (int stride = size >> 1; stride > 0; stride >>= 1) {
      __syncthreads();
      const int partner = tid ^ stride;
      if (partner > tid) {
        const u64 a = keys[tid], c = keys[partner];
        const bool desc = ((tid & size) == 0);
        if (desc ? (a < c) : (a > c)) { keys[tid] = c; keys[partner] = a; }
      }
    }
  }
  __syncthreads();
  if (tid < K_) cand[(size_t)(d * CHUNKS + chunk) * K_ + tid] = keys[tid];
}

// Kernel 2+3: one block per d. Wave 0 merges the 32 sorted candidate lists
// (32 rounds, barrier-free, keys unique so no tie handling); then gather
// top-32 rows, form samples, normalize, write nS. Block 0 zeroes out[0].
__global__ __launch_bounds__(256) void k23_topk_samples(const float* __restrict__ emb,
                                                        const u64* __restrict__ cand,
                                                        const float* __restrict__ sum_all,
                                                        float* __restrict__ nS,
                                                        float* __restrict__ out) {
  const int d = blockIdx.x;
  const int tid = threadIdx.x;
  const int lane = tid & 63;
  const int wave = tid >> 6;

  __shared__ u64 ck[CHUNKS * K_];  // 8 KB
  __shared__ int top[K_];
  __shared__ float w1[4], w2[4];
  __shared__ float inv1s, inv2s;

  for (int i = tid; i < CHUNKS * K_; i += 256)
    ck[i] = cand[(size_t)d * CHUNKS * K_ + i];

  const float s1 = sum_all[d * DIM_ + tid];

  __syncthreads();  // ck ready

  if (wave == 0) {
    // lane c < 32 owns sorted list c; 32 rounds of head-max.
    int h = 0;
    u64 cur = (lane < CHUNKS) ? ck[lane * K_] : 0ull;
    for (int k = 0; k < K_; ++k) {
      u64 m = cur;
#pragma unroll
      for (int off = 1; off < 32; off <<= 1) {
        const u64 o = __shfl_xor(m, off, 64);
        if (o > m) m = o;
      }
      const u64 bal = __ballot(lane < CHUNKS && cur == m);
      const int w = __ffsll(bal) - 1;
      if (lane == 0) top[k] = N_ - 1 - (int)(m & 0xFFFFFFFFull);
      if (lane == w) { ++h; cur = (h < K_) ? ck[lane * K_ + h] : 0ull; }
    }
  }
  __syncthreads();

  // Gather + samples + normalize.
  const float* base = emb + (size_t)d * N_ * DIM_;
  float ts = 0.f;
#pragma unroll 4
  for (int k = 0; k < K_; ++k) ts += base[(size_t)top[k] * DIM_ + tid];
  const float s2 = s1 - ts;

  float q1 = s1 * s1, q2 = s2 * s2;
#pragma unroll
  for (int off = 32; off > 0; off >>= 1) {
    q1 += __shfl_down(q1, off, 64);
    q2 += __shfl_down(q2, off, 64);
  }
  if (lane == 0) { w1[wave] = q1; w2[wave] = q2; }
  __syncthreads();
  if (tid == 0) {
    const float n1 = sqrtf(w1[0] + w1[1] + w1[2] + w1[3]);
    const float n2 = sqrtf(w2[0] + w2[1] + w2[2] + w2[3]);
    inv1s = 1.0f / fmaxf(n1, EPS_);
    inv2s = 1.0f / fmaxf(n2, EPS_);
    if (d == 0) out[0] = 0.0f;  // zero loss accumulator (ordered before k4)
  }
  __syncthreads();
  nS[d * DIM_ + tid] = s1 * inv1s;
  nS[(D_ + d) * DIM_ + tid] = s2 * inv2s;
}

// Loss kernel: 4 waves per pair; wave w handles 8 negatives for both sides
// with an online (max, sumexp) held uniformly in all lanes, combined via LDS.
__global__ __launch_bounds__(256) void k4_loss(const float* __restrict__ nS,
                                               const int* __restrict__ negidx,
                                               float* __restrict__ out) {
  const int p = blockIdx.x;
  const int tid = threadIdx.x;
  const int wave = tid >> 6;
  const int lane = tid & 63;

  const float4 vi = *reinterpret_cast<const float4*>(nS + p * DIM_ + (lane << 2));
  const float4 vj = *reinterpret_cast<const float4*>(nS + (p + L_) * DIM_ + (lane << 2));

  float dp = vi.x * vj.x + vi.y * vj.y + vi.z * vj.z + vi.w * vj.w;
#pragma unroll
  for (int off = 1; off < 64; off <<= 1) dp += __shfl_xor(dp, off, 64);
  const float invT = 1.0f / TEMP_;
  const float posT = dp * invT;

  float mi = -INFINITY, si = 0.f, mj = -INFINITY, sj = 0.f;
#pragma unroll
  for (int kk = 0; kk < K_ / 4; ++kk) {
    const int k = wave * (K_ / 4) + kk;
    const int idx = negidx[p * K_ + k];
    const float4 vn = *reinterpret_cast<const float4*>(nS + idx * DIM_ + (lane << 2));
    float di = vi.x * vn.x + vi.y * vn.y + vi.z * vn.z + vi.w * vn.w;
    float dj = vj.x * vn.x + vj.y * vn.y + vj.z * vn.z + vj.w * vn.w;
#pragma unroll
    for (int off = 1; off < 64; off <<= 1) {
      di += __shfl_xor(di, off, 64);
      dj += __shfl_xor(dj, off, 64);
    }
    const float li = di * invT;
    const float lj = dj * invT;
    if (li > mi) { si = si * expf(mi - li) + 1.f; mi = li; } else { si += expf(li - mi); }
    if (lj > mj) { sj = sj * expf(mj - lj) + 1.f; mj = lj; } else { sj += expf(lj - mj); }
  }

  __shared__ float pm[2][4], ps[2][4];
  if (lane == 0) {
    pm[0][wave] = mi; ps[0][wave] = si;
    pm[1][wave] = mj; ps[1][wave] = sj;
  }
  __syncthreads();
  if (tid == 0) {
    float total = 0.f;
#pragma unroll
    for (int side = 0; side < 2; ++side) {
      float m = posT;
      for (int w = 0; w < 4; ++w) m = fmaxf(m, pm[side][w]);
      float s = expf(posT - m);
      for (int w = 0; w < 4; ++w) s += ps[side][w] * expf(pm[side][w] - m);
      total += m + logf(s) - posT;  // lse - posT
    }
    atomicAdd(out, total / (2.0f * P_));
  }
}

extern "C" void kernel_launch(void* const* d_in, const int* in_sizes, int n_in,
                              void* d_out, int out_size, void* d_ws, size_t ws_size,
                              hipStream_t stream) {
  const float* emb = (const float*)d_in[0];
  const int* negidx = (const int*)d_in[1];
  float* out = (float*)d_out;

  // Workspace layout:
  u64* cand = (u64*)d_ws;                                   // 64*32*32 u64 = 512 KB
  float* sum_all = (float*)(cand + (size_t)D_ * CHUNKS * K_);  // 16 KB
  float* nS = sum_all + D_ * DIM_;                          // 128 KB

  hipMemsetAsync(sum_all, 0, D_ * DIM_ * sizeof(float), stream);

  k1_stream<<<D_ * CHUNKS, 256, 0, stream>>>(emb, cand, sum_all);
  k23_topk_samples<<<D_, 256, 0, stream>>>(emb, cand, sum_all, nS, out);
  k4_loss<<<P_, 256, 0, stream>>>(nS, negidx, out);
}